// Round 10
// baseline (21.626 us; speedup 1.0000x reference)
//
#include <hip/hip_runtime.h>
#include <math.h>

#define TT 512
#define EE 1024
#define AA 30

typedef float f32x4 __attribute__((ext_vector_type(4)));

static __device__ __forceinline__ float dot4(f32x4 p, f32x4 q) {
    return p.x * q.x + p.y * q.y + p.z * q.z + p.w * q.w;
}

// Fused single kernel: per wave = one span. Max-free softmax over rows:
//   sc_a = relu(x[b,st+a,:] . W + bias)  in [0, ~8]  -> exp never overflows fp32
//   out  = sum_a exp(sc_a) * x[b,st+a,:] / sum_a exp(sc_a)
template <int SWZ>
__global__ __launch_bounds__(256) void fused_span_kernel(const float* __restrict__ x,
                                                         const float* __restrict__ W,
                                                         const float* __restrict__ bias,
                                                         const int* __restrict__ start,
                                                         const int* __restrict__ end,
                                                         float* __restrict__ out,
                                                         int S, int G, int T) {
    int bid  = blockIdx.x;
    int wv   = threadIdx.x >> 6;     // 4 waves/block, 1 span/wave
    int lane = threadIdx.x & 63;
    int b, s, g;
    if (SWZ) {                       // bid&7 -> XCD; XCD 0-3 own b=0, XCD 4-7 own b=1
        int xcd = bid & 7;
        b = xcd >> 2;
        int local = ((bid >> 3) << 2) | (xcd & 3);   // [0, S/4)
        s = local * 4 + wv;
        g = b * S + s;
    } else {
        g = bid * 4 + wv;
        if (g >= G) return;
        b = g / S;
        s = g - b * S;
    }

    int st = start[s];
    int nA = min(end[s] - st + 1, AA);   // >=1; valid rows need no clamp (end <= T-1)

    // lane's slice: elements [4*lane + 256*c], c = 0..3  (wave covers all 1024)
    const f32x4* xb = reinterpret_cast<const f32x4*>(x + ((size_t)b * T + st) * EE) + lane;
    const f32x4* wp = reinterpret_cast<const f32x4*>(W) + lane;

    f32x4 w0 = wp[0], w1 = wp[64], w2 = wp[128], w3 = wp[192];
    f32x4 a0 = (f32x4)(0.f), a1 = (f32x4)(0.f), a2 = (f32x4)(0.f), a3 = (f32x4)(0.f);
    float sum = 0.f;
    float bsc = bias[0];

    int a = 0;
    for (; a + 4 <= nA; a += 4) {        // 16 independent loads in flight
        const f32x4* r0 = xb + (size_t)a * (EE / 4);
        const f32x4* r1 = r0 + (EE / 4);
        const f32x4* r2 = r1 + (EE / 4);
        const f32x4* r3 = r2 + (EE / 4);
        f32x4 v0 = r0[0], v1 = r0[64], v2 = r0[128], v3 = r0[192];
        f32x4 u0 = r1[0], u1 = r1[64], u2 = r1[128], u3 = r1[192];
        f32x4 p0 = r2[0], p1 = r2[64], p2 = r2[128], p3 = r2[192];
        f32x4 q0 = r3[0], q1 = r3[64], q2 = r3[128], q3 = r3[192];
        float d0 = dot4(v0, w0) + dot4(v1, w1) + dot4(v2, w2) + dot4(v3, w3);
        float d1 = dot4(u0, w0) + dot4(u1, w1) + dot4(u2, w2) + dot4(u3, w3);
        float d2 = dot4(p0, w0) + dot4(p1, w1) + dot4(p2, w2) + dot4(p3, w3);
        float d3 = dot4(q0, w0) + dot4(q1, w1) + dot4(q2, w2) + dot4(q3, w3);
        #pragma unroll
        for (int off = 32; off; off >>= 1) {     // four interleaved butterflies
            d0 += __shfl_xor(d0, off, 64);
            d1 += __shfl_xor(d1, off, 64);
            d2 += __shfl_xor(d2, off, 64);
            d3 += __shfl_xor(d3, off, 64);
        }
        float e0 = __expf(fmaxf(d0 + bsc, 0.f));
        float e1 = __expf(fmaxf(d1 + bsc, 0.f));
        float e2 = __expf(fmaxf(d2 + bsc, 0.f));
        float e3 = __expf(fmaxf(d3 + bsc, 0.f));
        sum += (e0 + e1) + (e2 + e3);
        a0 += e0 * v0 + e1 * u0 + e2 * p0 + e3 * q0;
        a1 += e0 * v1 + e1 * u1 + e2 * p1 + e3 * q1;
        a2 += e0 * v2 + e1 * u2 + e2 * p2 + e3 * q2;
        a3 += e0 * v3 + e1 * u3 + e2 * p3 + e3 * q3;
    }
    for (; a < nA; ++a) {
        const f32x4* r0 = xb + (size_t)a * (EE / 4);
        f32x4 v0 = r0[0], v1 = r0[64], v2 = r0[128], v3 = r0[192];
        float d0 = dot4(v0, w0) + dot4(v1, w1) + dot4(v2, w2) + dot4(v3, w3);
        #pragma unroll
        for (int off = 32; off; off >>= 1) d0 += __shfl_xor(d0, off, 64);
        float e0 = __expf(fmaxf(d0 + bsc, 0.f));
        sum += e0;
        a0 += e0 * v0;
        a1 += e0 * v1;
        a2 += e0 * v2;
        a3 += e0 * v3;
    }

    float inv = 1.0f / sum;              // sum >= exp(sc_0) >= 1, uniform across lanes
    f32x4* op = reinterpret_cast<f32x4*>(out + (size_t)g * EE) + lane;
    __builtin_nontemporal_store(a0 * inv, op);
    __builtin_nontemporal_store(a1 * inv, op + 64);
    __builtin_nontemporal_store(a2 * inv, op + 128);
    __builtin_nontemporal_store(a3 * inv, op + 192);
}

extern "C" void kernel_launch(void* const* d_in, const int* in_sizes, int n_in,
                              void* d_out, int out_size, void* d_ws, size_t ws_size,
                              hipStream_t stream) {
    const float* x     = (const float*)d_in[0];   // (B, T, E) f32
    const float* W     = (const float*)d_in[1];   // (E, 1)   f32
    const float* bias  = (const float*)d_in[2];   // (1,)     f32
    const int*   start = (const int*)d_in[3];     // (S,)     i32
    const int*   end   = (const int*)d_in[4];     // (S,)     i32
    float*       out   = (float*)d_out;           // (B, S, E) f32

    const int BT = in_sizes[0] / EE;              // B*T = 1024
    const int S  = in_sizes[3];                   // 2048
    const int B  = BT / TT;                       // 2
    const int G  = B * S;                         // 4096 spans
    const int T  = BT / B;

    if (B == 2 && S == 2048) {
        fused_span_kernel<1><<<G / 4, 256, 0, stream>>>(x, W, bias, start, end, out, S, G, T);
    } else {
        fused_span_kernel<0><<<(G + 3) / 4, 256, 0, stream>>>(x, W, bias, start, end, out, S, G, T);
    }
}

// Round 11
// 19.505 us; speedup vs baseline: 1.1087x; 1.1087x over previous
//
#include <hip/hip_runtime.h>
#include <math.h>

#define TT 512
#define EE 1024
#define AA 30

typedef float f32x4 __attribute__((ext_vector_type(4)));

static __device__ __forceinline__ float dot4(f32x4 p, f32x4 q) {
    return p.x * q.x + p.y * q.y + p.z * q.z + p.w * q.w;
}

// Fused: per wave = one span. Online (max-free) softmax over rows:
//   sc_a = relu(x[b,st+a,:] . W + bias)  in [0, ~8]  -> exp never overflows fp32
//   out  = sum_a exp(sc_a) * x[b,st+a,:] / sum_a exp(sc_a)
// One kernel, no workspace, no inter-kernel dependency.
template <int SWZ>
__global__ __launch_bounds__(256) void fused_span_kernel(const float* __restrict__ x,
                                                         const float* __restrict__ W,
                                                         const float* __restrict__ bias,
                                                         const int* __restrict__ start,
                                                         const int* __restrict__ end,
                                                         float* __restrict__ out,
                                                         int S, int G) {
    int bid  = blockIdx.x;
    int wv   = threadIdx.x >> 6;     // 4 waves/block, 1 span/wave
    int lane = threadIdx.x & 63;
    int b, s, g;
    if (SWZ) {                       // bid&7 -> XCD; XCD 0-3 own b=0, XCD 4-7 own b=1
        int xcd = bid & 7;
        b = xcd >> 2;
        int local = ((bid >> 3) << 2) | (xcd & 3);   // [0, S/4)
        s = local * 4 + wv;
        g = b * S + s;
    } else {
        g = bid * 4 + wv;
        if (g >= G) return;
        b = g / S;
        s = g - b * S;
    }

    int st = start[s];
    int nA = min(end[s] - st + 1, AA);   // >=1; valid rows need no clamp (end <= T-1)

    // lane's slice: elements [4*lane + 256*c], c = 0..3  (wave covers all 1024)
    const f32x4* xb = reinterpret_cast<const f32x4*>(x + ((size_t)b * TT + st) * EE) + lane;
    const f32x4* wp = reinterpret_cast<const f32x4*>(W) + lane;

    f32x4 w0 = wp[0], w1 = wp[64], w2 = wp[128], w3 = wp[192];
    f32x4 a0 = (f32x4)(0.f), a1 = (f32x4)(0.f), a2 = (f32x4)(0.f), a3 = (f32x4)(0.f);
    float sum = 0.f;
    float bsc = bias[0];

    int a = 0;
    for (; a + 2 <= nA; a += 2) {        // 8 independent loads in flight
        const f32x4* r0 = xb + (size_t)a * (EE / 4);
        const f32x4* r1 = r0 + (EE / 4);
        f32x4 v0 = r0[0], v1 = r0[64], v2 = r0[128], v3 = r0[192];
        f32x4 u0 = r1[0], u1 = r1[64], u2 = r1[128], u3 = r1[192];
        float d0 = dot4(v0, w0) + dot4(v1, w1) + dot4(v2, w2) + dot4(v3, w3);
        float d1 = dot4(u0, w0) + dot4(u1, w1) + dot4(u2, w2) + dot4(u3, w3);
        #pragma unroll
        for (int off = 32; off; off >>= 1) {     // two interleaved butterflies
            d0 += __shfl_xor(d0, off, 64);
            d1 += __shfl_xor(d1, off, 64);
        }
        float p0 = __expf(fmaxf(d0 + bsc, 0.f));
        float p1 = __expf(fmaxf(d1 + bsc, 0.f));
        sum += p0 + p1;
        a0 += p0 * v0 + p1 * u0;
        a1 += p0 * v1 + p1 * u1;
        a2 += p0 * v2 + p1 * u2;
        a3 += p0 * v3 + p1 * u3;
    }
    if (a < nA) {
        const f32x4* r0 = xb + (size_t)a * (EE / 4);
        f32x4 v0 = r0[0], v1 = r0[64], v2 = r0[128], v3 = r0[192];
        float d0 = dot4(v0, w0) + dot4(v1, w1) + dot4(v2, w2) + dot4(v3, w3);
        #pragma unroll
        for (int off = 32; off; off >>= 1) d0 += __shfl_xor(d0, off, 64);
        float p0 = __expf(fmaxf(d0 + bsc, 0.f));
        sum += p0;
        a0 += p0 * v0;
        a1 += p0 * v1;
        a2 += p0 * v2;
        a3 += p0 * v3;
    }

    float inv = 1.0f / sum;              // sum >= exp(sc_0) >= 1, uniform across lanes
    f32x4* op = reinterpret_cast<f32x4*>(out + (size_t)g * EE) + lane;
    __builtin_nontemporal_store(a0 * inv, op);
    __builtin_nontemporal_store(a1 * inv, op + 64);
    __builtin_nontemporal_store(a2 * inv, op + 128);
    __builtin_nontemporal_store(a3 * inv, op + 192);
}

extern "C" void kernel_launch(void* const* d_in, const int* in_sizes, int n_in,
                              void* d_out, int out_size, void* d_ws, size_t ws_size,
                              hipStream_t stream) {
    const float* x     = (const float*)d_in[0];   // (B, T, E) f32
    const float* W     = (const float*)d_in[1];   // (E, 1)   f32
    const float* bias  = (const float*)d_in[2];   // (1,)     f32
    const int*   start = (const int*)d_in[3];     // (S,)     i32
    const int*   end   = (const int*)d_in[4];     // (S,)     i32
    float*       out   = (float*)d_out;           // (B, S, E) f32

    const int BT = in_sizes[0] / EE;              // B*T = 1024
    const int S  = in_sizes[3];                   // 2048
    const int B  = BT / TT;                       // 2
    const int G  = B * S;                         // 4096 spans

    if (B == 2 && S == 2048) {
        fused_span_kernel<1><<<G / 4, 256, 0, stream>>>(x, W, bias, start, end, out, S, G);
    } else {
        fused_span_kernel<0><<<(G + 3) / 4, 256, 0, stream>>>(x, W, bias, start, end, out, S, G);
    }
}